// Round 16
// baseline (1487.606 us; speedup 1.0000x reference)
//
#include <hip/hip_runtime.h>
#include <hip/hip_bf16.h>
#include <math.h>

#define B_ 4
#define L_ 1024
#define N_ 4096
#define D_ 1024
#define H_ 16
#define FF_ 2752
#define NL_ 2
#define HD_ 64
#define M_ (B_*N_)   // 16384

typedef short bf16x8 __attribute__((ext_vector_type(8)));
typedef float f32x4 __attribute__((ext_vector_type(4)));

__device__ __forceinline__ float bf2f(short s){
  unsigned int u = ((unsigned int)(unsigned short)s) << 16;
  union { unsigned int u; float f; } c; c.u = u; return c.f;
}
__device__ __forceinline__ short f2bf(float f){
  union { float f; unsigned int u; } c; c.f = f;
  unsigned int u = c.u;
  unsigned int r = (u + 0x7fffu + ((u >> 16) & 1u)) >> 16;
  return (short)r;
}

#define GPTR(p) ((const __attribute__((address_space(1))) void*)(p))
#define LPTR(p) ((__attribute__((address_space(3))) void*)(p))

// ---------------- gather + rope table (merged launch) ----------------
__global__ __launch_bounds__(256) void gather2_kernel(const float* __restrict__ zh,
                                                      const float* __restrict__ src,
                                                      float* __restrict__ z,
                                                      float* __restrict__ cost,
                                                      float* __restrict__ sint){
  int bid = blockIdx.x;
  if (bid < 16384) {
    int idx = bid*256 + threadIdx.x;
    int d4 = idx & (D_/4 - 1);
    int n  = (idx >> 8) & (N_-1);
    int b  = idx >> 20;
    int l  = n >> 2;
    float s = src[((size_t)b*L_ + l)*N_ + n];
    float4 zv = *(const float4*)(zh + ((size_t)b*L_ + l)*D_ + d4*4);
    float4 o; o.x=zv.x*s; o.y=zv.y*s; o.z=zv.z*s; o.w=zv.w*s;
    *(float4*)(z + ((size_t)b*N_ + n)*D_ + d4*4) = o;
  } else {
    int idx = (bid-16384)*256 + threadIdx.x;   // N_*32 = 131072
    int n = idx >> 5, j = idx & 31;
    float inv = __expf(-(float)j * (9.210340371976184f/32.0f));
    float ang = (float)n * inv;
    cost[idx] = cosf(ang);
    sint[idx] = sinf(ang);
  }
}

// -------- batched transpose + fp32->bf16 --------
__global__ void tconv_kernel(const float* __restrict__ i0, const float* __restrict__ i1,
                             const float* __restrict__ i2, const float* __restrict__ i3,
                             short* __restrict__ o0, short* __restrict__ o1,
                             short* __restrict__ o2, short* __restrict__ o3,
                             int K, int Nc, int ldo, int bs, int gs, int go0, int gostep){
  __shared__ float tile[32][33];
  const float* in = (blockIdx.z==0) ? i0 : (blockIdx.z==1) ? i1 : (blockIdx.z==2) ? i2 : i3;
  short* out      = (blockIdx.z==0) ? o0 : (blockIdx.z==1) ? o1 : (blockIdx.z==2) ? o2 : o3;
  int go = go0 + (int)blockIdx.z * gostep;
  int k0 = blockIdx.x*32, r0 = blockIdx.y*32;
  int tx = threadIdx.x, ty = threadIdx.y;
  for (int i = ty; i < 32; i += 8)
    tile[i][tx] = in[(size_t)(k0+i)*Nc + r0 + tx];
  __syncthreads();
  for (int i = ty; i < 32; i += 8){
    int rr = r0 + i;
    int orow = (rr/bs)*gs + go + (rr % bs);
    out[(size_t)orow*ldo + k0 + tx] = f2bf(tile[tx][i]);
  }
}

// ---------------- rmsnorm ----------------
__global__ __launch_bounds__(256) void rmsnorm_kernel(const float* __restrict__ z,
                                                      const float* __restrict__ w,
                                                      short* __restrict__ out){
  int row = blockIdx.x, tid = threadIdx.x;
  const float* x = z + (size_t)row*D_;
  float4 v = *(const float4*)(x + tid*4);
  float ss = v.x*v.x + v.y*v.y + v.z*v.z + v.w*v.w;
  #pragma unroll
  for (int off=32; off>0; off>>=1) ss += __shfl_down(ss, off, 64);
  __shared__ float red[4];
  if ((tid & 63) == 0) red[tid>>6] = ss;
  __syncthreads();
  float ms = (red[0]+red[1]+red[2]+red[3]) * (1.0f/D_);
  float rs = rsqrtf(ms + 1e-6f);
  float4 wv = *(const float4*)(w + tid*4);
  short4 o;
  o.x = f2bf(v.x*rs*wv.x); o.y = f2bf(v.y*rs*wv.y);
  o.z = f2bf(v.z*rs*wv.z); o.w = f2bf(v.w*rs*wv.w);
  *(short4*)(out + (size_t)row*D_ + tid*4) = o;
}

// ---------------- GEMM (2-phase 128xBN), XCD row-slice + col-outer/row-inner RG groups ----------
// XCD k owns ny/8 contiguous row-blocks. Within: row-groups of RG; per group, columns walk
// with RG rows inner (serpentine). B-block reused RG x back-to-back; A-slice L2-resident.
// BN=128: 4 waves/EU (occupancy-verified r15: VGPR 60 + 64 AGPR fits 128/wave, 4 blocks/CU).
// BN=64: 5 waves/EU (acc only 32 AGPR -> ~92/wave fits 102 budget).
// EPI 0: store bf16 | EPI 1: fp32 += | EPI 2: swiglu pairs (BN=128) | EPI 3: rope(q,k)+qscale
template<int EPI, int BN>
__global__ __launch_bounds__(256, (BN == 128) ? 4 : 5) void gemm_bt_kernel(
    const short* __restrict__ A, int lda,
    const short* __restrict__ Bt, int ldb,
    void* __restrict__ Cout, int ldc, int K, int nx, int ny, int RG,
    const float* __restrict__ cosT, const float* __restrict__ sinT)
{
  constexpr int WC = (BN == 128) ? 2 : 1;
  constexpr int MI = (BN == 128) ? 4 : 2;
  constexpr int NI = 4;
  __shared__ short Al[128*64];
  __shared__ short Bl[BN*64];
  const int tid = threadIdx.x;
  const int wid = tid >> 6;
  const int lane = tid & 63;
  const int wr = wid / WC, wc = wid % WC;
  const int lrow = lane & 15;
  const int lk   = (lane >> 4) << 3;

  // XCD-sliced, col-outer/row-inner group order (bijective; requires ny%8==0, (ny/8)%RG==0)
  int bx, by;
  {
    const int lin = blockIdx.x;
    const int xcd = lin & 7;
    const int t   = lin >> 3;            // chunk-local, [0, nx*(ny/8))
    const int rpx = ny >> 3;             // row-blocks per XCD
    const int gsz = RG * nx;
    int g   = t / gsz;
    int rem = t - g*gsz;
    int c   = rem / RG;
    int rl  = rem - c*RG;
    if (c & 1) rl = RG - 1 - rl;
    if (g & 1) c = nx - 1 - c;
    by = xcd*rpx + g*RG + rl;
    bx = c;
  }

  f32x4 acc[MI][NI];
  #pragma unroll
  for (int i=0;i<MI;i++)
    #pragma unroll
    for (int j=0;j<NI;j++) acc[i][j] = (f32x4){0.f,0.f,0.f,0.f};

  const size_t abase = (size_t)by * 128 * lda;
  const size_t bbase = (size_t)bx * BN  * ldb;

  for (int kt = 0; kt < K; kt += 64) {
    __syncthreads();
    #pragma unroll
    for (int r = 0; r < 4; ++r) {
      int l2 = (r<<8) + tid;
      int row = l2 >> 3, seg = l2 & 7;
      const short* ga = A + abase + (size_t)row*lda + kt + (seg<<3);
      int lbase = (r<<11) + (wid<<9);
      __builtin_amdgcn_global_load_lds(GPTR(ga), LPTR(Al + lbase), 16, 0, 0);
    }
    #pragma unroll
    for (int r = 0; r < BN/32; ++r) {
      int l2 = (r<<8) + tid;
      int row = l2 >> 3, seg = l2 & 7;
      const short* gb = Bt + bbase + (size_t)row*ldb + kt + (seg<<3);
      int lbase = (r<<11) + (wid<<9);
      __builtin_amdgcn_global_load_lds(GPTR(gb), LPTR(Bl + lbase), 16, 0, 0);
    }
    __syncthreads();

    #pragma unroll
    for (int kk = 0; kk < 64; kk += 32) {
      bf16x8 af[MI], bfr[NI];
      #pragma unroll
      for (int mi=0;mi<MI;mi++){
        int row = wr*(MI*16) + (mi<<4) + lrow;
        af[mi] = *(const bf16x8*)(Al + row*64 + kk + lk);
      }
      #pragma unroll
      for (int ni=0;ni<NI;ni++){
        int row = wc*(NI*16) + (ni<<4) + lrow;
        bfr[ni] = *(const bf16x8*)(Bl + row*64 + kk + lk);
      }
      #pragma unroll
      for (int mi=0;mi<MI;mi++)
        #pragma unroll
        for (int ni=0;ni<NI;ni++)
          acc[mi][ni] = __builtin_amdgcn_mfma_f32_16x16x32_bf16(af[mi], bfr[ni], acc[mi][ni], 0, 0, 0);
    }
  }

  const int crow0 = by*128 + wr*(MI*16);
  const int ccol0 = bx*BN  + wc*(NI*16);

  if (EPI == 2) {
    #pragma unroll
    for (int mi=0;mi<MI;mi++){
      #pragma unroll
      for (int p=0;p<NI/2;p++){
        int fcol = (ccol0>>1) + (p<<4) + lrow;
        int rowb = crow0 + (mi<<4) + ((lane>>4)<<2);
        #pragma unroll
        for (int v=0;v<4;v++){
          float g = acc[mi][2*p][v], u = acc[mi][2*p+1][v];
          float a = g * u / (1.0f + __expf(-g));
          ((short*)Cout)[(size_t)(rowb+v)*ldc + fcol] = f2bf(a);
        }
      }
    }
  } else if (EPI == 3) {
    #pragma unroll
    for (int mi=0;mi<MI;mi++){
      #pragma unroll
      for (int ni=0;ni<NI;ni++){
        int col  = ccol0 + (ni<<4) + lrow;
        int rowb = crow0 + (mi<<4) + ((lane>>4)<<2);
        bool qk = (col < 2048);
        int jhd = (col >> 1) & 31;
        #pragma unroll
        for (int v=0;v<4;v++){
          float val = acc[mi][ni][v];
          int row = rowb + v;
          int trow = row & (N_-1);             // position within batch
          float partner = __shfl_xor(val, 1, 64);
          if (qk) {
            float cc = cosT[(trow<<5)+jhd], ssn = sinT[(trow<<5)+jhd];
            float r = (lane & 1) ? (val*cc + partner*ssn) : (val*cc - partner*ssn);
            val = (col < 1024) ? r*0.125f : r;
          }
          ((short*)Cout)[(size_t)row*ldc + col] = f2bf(val);
        }
      }
    }
  } else {
    #pragma unroll
    for (int mi=0;mi<MI;mi++){
      #pragma unroll
      for (int ni=0;ni<NI;ni++){
        int col  = ccol0 + (ni<<4) + lrow;
        int rowb = crow0 + (mi<<4) + ((lane>>4)<<2);
        #pragma unroll
        for (int v=0;v<4;v++){
          float val = acc[mi][ni][v];
          int row = rowb + v;
          if (EPI == 0) ((short*)Cout)[(size_t)row*ldc + col] = f2bf(val);
          else          ((float*)Cout)[(size_t)row*ldc + col] += val;
        }
      }
    }
  }
}

// ---------------- sliding-window attention: f32-K LDS (chunk-XOR), 2 lanes/query ----------------
// Rows are global; window is clamped to the 4096-row batch segment.
#define QB_ 128
__global__ __launch_bounds__(256, 2) void attn_kernel(const short* __restrict__ qkv,
                                                      short* __restrict__ o){
  __shared__ float Kf[160*68];
  __shared__ short Vl[160*72];
  const int h  = blockIdx.y;
  const int n0 = blockIdx.x * QB_;
  const int lo = n0 & ~(N_-1);
  const int hi = lo + N_ - 1;
  const int tid = threadIdx.x;

  for (int i = tid; i < 1280; i += 256){
    int r = i >> 3, g = i & 7;
    int m = n0 - 16 + r;
    int mc = m < lo ? lo : (m > hi ? hi : m);
    bf16x8 kv = *(const bf16x8*)(qkv + (size_t)mc*3072 + 1024 + h*64 + (g<<3));
    bf16x8 vv = *(const bf16x8*)(qkv + (size_t)mc*3072 + 2048 + h*64 + (g<<3));
    int sw = ((r>>3)&3)<<1;
    float4 lof, hif;
    lof.x=bf2f(kv[0]); lof.y=bf2f(kv[1]); lof.z=bf2f(kv[2]); lof.w=bf2f(kv[3]);
    hif.x=bf2f(kv[4]); hif.y=bf2f(kv[5]); hif.z=bf2f(kv[6]); hif.w=bf2f(kv[7]);
    *(float4*)(Kf + r*68 + (((2*g)   ^ sw)<<2)) = lof;
    *(float4*)(Kf + r*68 + (((2*g+1) ^ sw)<<2)) = hif;
    *(bf16x8*)(Vl + r*72 + (g<<3)) = vv;
  }
  __syncthreads();

  const int q  = tid >> 1;
  const int dh = tid & 1;
  const int nc = n0 + q;

  const short* qp = qkv + (size_t)nc*3072 + h*64 + dh*32;
  float qr[32];
  #pragma unroll
  for (int i=0;i<4;i++){
    bf16x8 qv = *(const bf16x8*)(qp + i*8);
    #pragma unroll
    for (int t=0;t<8;t++) qr[i*8+t] = bf2f(qv[t]);
  }

  float sc[31];
  float mx = -1e30f;
  #pragma unroll
  for (int t=0;t<31;t++){
    int m = nc - 15 + t;
    int r = q + 1 + t;
    int sw = ((r>>3)&3)<<1;
    const float* kp = Kf + r*68;
    float dot = 0.f;
    #pragma unroll
    for (int i=0;i<8;i++){
      float4 kv4 = *(const float4*)(kp + (((dh*8+i)^sw)<<2));
      dot += qr[i*4+0]*kv4.x + qr[i*4+1]*kv4.y + qr[i*4+2]*kv4.z + qr[i*4+3]*kv4.w;
    }
    dot += __shfl_xor(dot, 1, 64);
    bool valid = (m>=lo) && (m<=hi);
    sc[t] = valid ? dot : -1e30f;
    mx = fmaxf(mx, sc[t]);
  }
  float sum = 0.f;
  #pragma unroll
  for (int t=0;t<31;t++){ sc[t] = __expf(sc[t]-mx); sum += sc[t]; }
  float inv = 1.0f/sum;

  float ov[32];
  #pragma unroll
  for (int i=0;i<32;i++) ov[i]=0.f;
  #pragma unroll
  for (int t=0;t<31;t++){
    const short* vp = Vl + (q + 1 + t)*72 + dh*32;
    float p = sc[t]*inv;
    #pragma unroll
    for (int i=0;i<4;i++){
      bf16x8 vv = *(const bf16x8*)(vp + i*8);
      #pragma unroll
      for (int u=0;u<8;u++) ov[i*8+u] += p * bf2f(vv[u]);
    }
  }
  short* op = o + (size_t)nc*1024 + h*64 + dh*32;
  #pragma unroll
  for (int i=0;i<4;i++){
    bf16x8 wv;
    #pragma unroll
    for (int u=0;u<8;u++) wv[u] = f2bf(ov[i*8+u]);
    *(bf16x8*)(op + i*8) = wv;
  }
}

// ---------------- final rmsnorm + head matmul (V=6), fp32 ----------------
__global__ __launch_bounds__(256) void head_kernel(const float* __restrict__ z,
                                                   const float* __restrict__ fw,
                                                   const float* __restrict__ hw,
                                                   float* __restrict__ out){
  int row = blockIdx.x, tid = threadIdx.x;
  const float* x = z + (size_t)row*D_;
  float4 v = *(const float4*)(x + tid*4);
  float ss = v.x*v.x + v.y*v.y + v.z*v.z + v.w*v.w;
  #pragma unroll
  for (int off=32; off>0; off>>=1) ss += __shfl_down(ss, off, 64);
  __shared__ float red[4];
  if ((tid & 63) == 0) red[tid>>6] = ss;
  __syncthreads();
  float ms = (red[0]+red[1]+red[2]+red[3]) * (1.0f/D_);
  float rs = rsqrtf(ms + 1e-6f);
  float4 wv = *(const float4*)(fw + tid*4);
  float h0 = v.x*rs*wv.x, h1 = v.y*rs*wv.y, h2 = v.z*rs*wv.z, h3 = v.w*rs*wv.w;
  float p[6];
  #pragma unroll
  for (int t=0;t<6;t++){
    const float* hp = hw + (size_t)(tid*4)*6 + t;
    p[t] = h0*hp[0] + h1*hp[6] + h2*hp[12] + h3*hp[18];
  }
  #pragma unroll
  for (int t=0;t<6;t++)
    #pragma unroll
    for (int off=32; off>0; off>>=1) p[t] += __shfl_down(p[t], off, 64);
  __shared__ float wred[4][6];
  if ((tid & 63) == 0)
    #pragma unroll
    for (int t=0;t<6;t++) wred[tid>>6][t] = p[t];
  __syncthreads();
  if (tid < 6)
    out[(size_t)row*6 + tid] = wred[0][tid]+wred[1][tid]+wred[2][tid]+wred[3][tid];
}

extern "C" void kernel_launch(void* const* d_in, const int* in_sizes, int n_in,
                              void* d_out, int out_size, void* d_ws, size_t ws_size,
                              hipStream_t stream)
{
  (void)in_sizes; (void)n_in; (void)out_size;
  const float* z_hat  = (const float*)d_in[0];
  const float* source = (const float*)d_in[1];
  const float* wq  = (const float*)d_in[2];
  const float* wk  = (const float*)d_in[3];
  const float* wvp = (const float*)d_in[4];
  const float* wo  = (const float*)d_in[5];
  const float* n1w = (const float*)d_in[6];
  const float* n2w = (const float*)d_in[7];
  const float* w1  = (const float*)d_in[8];
  const float* w3  = (const float*)d_in[9];
  const float* w2  = (const float*)d_in[10];
  const float* fnw = (const float*)d_in[11];
  const float* hw  = (const float*)d_in[12];
  float* out = (float*)d_out;
  char* ws = (char*)d_ws;
  dim3 tb(32,8);

  const bool fullM = (ws_size >= 219283456ULL);

  if (fullM) {
    // ---- full-M layout: 219.3 MB ----
    float* z     = (float*)(ws);                      // 67,108,864
    short* h     = (short*)(ws + 67108864);           // 33,554,432  [16384][1024] (doubles as o)
    short* qkv   = (short*)(ws + 100663296);          // 100,663,296 [16384][3072] (shared with act)
    short* act   = qkv;                               //             [16384][2752]
    short* qkvW  = (short*)(ws + 201326592);          //  6,291,456
    short* woW   = (short*)(ws + 207618048);          //  2,097,152
    short* w13W  = (short*)(ws + 201326592);          // 11,272,192  (stage B reuse)
    short* w2W   = (short*)(ws + 212598784);          //  5,636,096
    float* cosT  = (float*)(ws + 218234880);
    float* sinT  = (float*)(ws + 218759168);

    gather2_kernel<<<16896,256,0,stream>>>(z_hat, source, z, cosT, sinT);

    for (int l=0; l<NL_; l++){
      size_t wofs = (size_t)l*D_*D_;
      tconv_kernel<<<dim3(32,32,4),tb,0,stream>>>(
          wq + wofs, wk + wofs, wvp + wofs, wo + wofs,
          qkvW, qkvW + 1024*1024, qkvW + 2048*1024, woW,
          1024,1024,1024, 64,64, 0,0);
      // stage A
      rmsnorm_kernel<<<M_,256,0,stream>>>(z, n1w + l*D_, h);
      gemm_bt_kernel<3,128><<<3072,256,0,stream>>>(h,1024, qkvW,1024, qkv,3072, 1024, 24,128,16, cosT, sinT);
      attn_kernel<<<dim3(M_/QB_,H_),256,0,stream>>>(qkv, h);          // o overwrites h (h dead)
      gemm_bt_kernel<1,64><<<2048,256,0,stream>>>(h,1024, woW,1024, z,1024, 1024, 16,128,16, cosT, sinT);
      // stage B weights
      tconv_kernel<<<dim3(32,86,2),tb,0,stream>>>(
          w1 + (size_t)l*D_*FF_, w3 + (size_t)l*D_*FF_, w1, w1,
          w13W, w13W, w13W, w13W,
          1024,2752,1024, 16,32, 0,16);
      tconv_kernel<<<dim3(86,32,1),tb,0,stream>>>(
          w2 + (size_t)l*FF_*D_, w2, w2, w2,
          w2W, w2W, w2W, w2W,
          2752,1024,2752, 64,64, 0,0);
      // stage B
      rmsnorm_kernel<<<M_,256,0,stream>>>(z, n2w + l*D_, h);
      gemm_bt_kernel<2,128><<<5504,256,0,stream>>>(h,1024, w13W,1024, act,2752, 1024, 43,128,16, cosT, sinT);
      gemm_bt_kernel<1,64><<<2048,256,0,stream>>>(act,2752, w2W,2752, z,1024, 2752, 16,128,4, cosT, sinT);
    }
    head_kernel<<<M_,256,0,stream>>>(z, fnw, hw, out);

  } else {
    // ---- per-batch layout (121 MiB) ----
    float* z     = (float*)(ws);
    short* h_b   = (short*)(ws + 67108864);
    short* qkv_b = (short*)(ws + 75497472);
    short* act_b = qkv_b;
    short* o_b   = (short*)(ws + 100663296);
    short* qkvW  = (short*)(ws + 109051904);
    short* woW   = (short*)(ws + 115343360);
    short* w13W  = (short*)(ws + 109051904);
    short* w2W   = (short*)(ws + 120324096);
    float* cosT  = (float*)(ws + 125960192);
    float* sinT  = (float*)(ws + 126484480);

    gather2_kernel<<<16896,256,0,stream>>>(z_hat, source, z, cosT, sinT);

    for (int l=0; l<NL_; l++){
      size_t wofs = (size_t)l*D_*D_;
      tconv_kernel<<<dim3(32,32,4),tb,0,stream>>>(
          wq + wofs, wk + wofs, wvp + wofs, wo + wofs,
          qkvW, qkvW + 1024*1024, qkvW + 2048*1024, woW,
          1024,1024,1024, 64,64, 0,0);
      for (int b=0; b<B_; b++){
        float* zb = z + (size_t)b*N_*D_;
        rmsnorm_kernel<<<N_,256,0,stream>>>(zb, n1w + l*D_, h_b);
        gemm_bt_kernel<3,128><<<768,256,0,stream>>>(h_b,1024, qkvW,1024, qkv_b,3072, 1024, 24,32,4, cosT, sinT);
        attn_kernel<<<dim3(N_/QB_,H_),256,0,stream>>>(qkv_b, o_b);
        gemm_bt_kernel<1,64><<<512,256,0,stream>>>(o_b,1024, woW,1024, zb,1024, 1024, 16,32,4, cosT, sinT);
      }
      tconv_kernel<<<dim3(32,86,2),tb,0,stream>>>(
          w1 + (size_t)l*D_*FF_, w3 + (size_t)l*D_*FF_, w1, w1,
          w13W, w13W, w13W, w13W,
          1024,2752,1024, 16,32, 0,16);
      tconv_kernel<<<dim3(86,32,1),tb,0,stream>>>(
          w2 + (size_t)l*FF_*D_, w2, w2, w2,
          w2W, w2W, w2W, w2W,
          2752,1024,2752, 64,64, 0,0);
      for (int b=0; b<B_; b++){
        float* zb = z + (size_t)b*N_*D_;
        rmsnorm_kernel<<<N_,256,0,stream>>>(zb, n2w + l*D_, h_b);
        gemm_bt_kernel<2,128><<<1376,256,0,stream>>>(h_b,1024, w13W,1024, act_b,2752, 1024, 43,32,4, cosT, sinT);
        gemm_bt_kernel<1,64><<<512,256,0,stream>>>(act_b,2752, w2W,2752, zb,1024, 2752, 16,32,4, cosT, sinT);
      }
    }
    head_kernel<<<M_,256,0,stream>>>(z, fnw, hw, out);
  }
}

// Round 17
// 1364.591 us; speedup vs baseline: 1.0901x; 1.0901x over previous
//
#include <hip/hip_runtime.h>
#include <hip/hip_bf16.h>
#include <math.h>

#define B_ 4
#define L_ 1024
#define N_ 4096
#define D_ 1024
#define H_ 16
#define FF_ 2752
#define NL_ 2
#define HD_ 64
#define M_ (B_*N_)   // 16384

typedef short bf16x8 __attribute__((ext_vector_type(8)));
typedef float f32x4 __attribute__((ext_vector_type(4)));

__device__ __forceinline__ float bf2f(short s){
  unsigned int u = ((unsigned int)(unsigned short)s) << 16;
  union { unsigned int u; float f; } c; c.u = u; return c.f;
}
__device__ __forceinline__ short f2bf(float f){
  union { float f; unsigned int u; } c; c.f = f;
  unsigned int u = c.u;
  unsigned int r = (u + 0x7fffu + ((u >> 16) & 1u)) >> 16;
  return (short)r;
}

#define GPTR(p) ((const __attribute__((address_space(1))) void*)(p))
#define LPTR(p) ((__attribute__((address_space(3))) void*)(p))

// ---------------- gather + rope table (merged launch) ----------------
__global__ __launch_bounds__(256) void gather2_kernel(const float* __restrict__ zh,
                                                      const float* __restrict__ src,
                                                      float* __restrict__ z,
                                                      float* __restrict__ cost,
                                                      float* __restrict__ sint){
  int bid = blockIdx.x;
  if (bid < 16384) {
    int idx = bid*256 + threadIdx.x;
    int d4 = idx & (D_/4 - 1);
    int n  = (idx >> 8) & (N_-1);
    int b  = idx >> 20;
    int l  = n >> 2;
    float s = src[((size_t)b*L_ + l)*N_ + n];
    float4 zv = *(const float4*)(zh + ((size_t)b*L_ + l)*D_ + d4*4);
    float4 o; o.x=zv.x*s; o.y=zv.y*s; o.z=zv.z*s; o.w=zv.w*s;
    *(float4*)(z + ((size_t)b*N_ + n)*D_ + d4*4) = o;
  } else {
    int idx = (bid-16384)*256 + threadIdx.x;   // N_*32 = 131072
    int n = idx >> 5, j = idx & 31;
    float inv = __expf(-(float)j * (9.210340371976184f/32.0f));
    float ang = (float)n * inv;
    cost[idx] = cosf(ang);
    sint[idx] = sinf(ang);
  }
}

// -------- batched transpose + fp32->bf16 --------
__global__ void tconv_kernel(const float* __restrict__ i0, const float* __restrict__ i1,
                             const float* __restrict__ i2, const float* __restrict__ i3,
                             short* __restrict__ o0, short* __restrict__ o1,
                             short* __restrict__ o2, short* __restrict__ o3,
                             int K, int Nc, int ldo, int bs, int gs, int go0, int gostep){
  __shared__ float tile[32][33];
  const float* in = (blockIdx.z==0) ? i0 : (blockIdx.z==1) ? i1 : (blockIdx.z==2) ? i2 : i3;
  short* out      = (blockIdx.z==0) ? o0 : (blockIdx.z==1) ? o1 : (blockIdx.z==2) ? o2 : o3;
  int go = go0 + (int)blockIdx.z * gostep;
  int k0 = blockIdx.x*32, r0 = blockIdx.y*32;
  int tx = threadIdx.x, ty = threadIdx.y;
  for (int i = ty; i < 32; i += 8)
    tile[i][tx] = in[(size_t)(k0+i)*Nc + r0 + tx];
  __syncthreads();
  for (int i = ty; i < 32; i += 8){
    int rr = r0 + i;
    int orow = (rr/bs)*gs + go + (rr % bs);
    out[(size_t)orow*ldo + k0 + tx] = f2bf(tile[tx][i]);
  }
}

// ---------------- rmsnorm ----------------
__global__ __launch_bounds__(256) void rmsnorm_kernel(const float* __restrict__ z,
                                                      const float* __restrict__ w,
                                                      short* __restrict__ out){
  int row = blockIdx.x, tid = threadIdx.x;
  const float* x = z + (size_t)row*D_;
  float4 v = *(const float4*)(x + tid*4);
  float ss = v.x*v.x + v.y*v.y + v.z*v.z + v.w*v.w;
  #pragma unroll
  for (int off=32; off>0; off>>=1) ss += __shfl_down(ss, off, 64);
  __shared__ float red[4];
  if ((tid & 63) == 0) red[tid>>6] = ss;
  __syncthreads();
  float ms = (red[0]+red[1]+red[2]+red[3]) * (1.0f/D_);
  float rs = rsqrtf(ms + 1e-6f);
  float4 wv = *(const float4*)(w + tid*4);
  short4 o;
  o.x = f2bf(v.x*rs*wv.x); o.y = f2bf(v.y*rs*wv.y);
  o.z = f2bf(v.z*rs*wv.z); o.w = f2bf(v.w*rs*wv.w);
  *(short4*)(out + (size_t)row*D_ + tid*4) = o;
}

// ---------------- GEMM (2-phase 128xBN), XOR-swizzled LDS, XCD row-slice RG order ----------
// LDS layout: [row][64] with column ^ ((row&7)<<3), applied via pre-swizzled GLOBAL source
// (LDS dest linear for global_load_lds) and matching XOR on ds_read. Fragment rows have
// row&7 == lrow&7, so the involution cancels; kills the 16-way stride-128B bank conflict.
// BN=128: 4 waves/EU | BN=64: 5 waves/EU (both occupancy-verified r15/r16).
// EPI 0: store bf16 | EPI 1: fp32 += | EPI 2: swiglu pairs (BN=128) | EPI 3: rope(q,k)+qscale
template<int EPI, int BN>
__global__ __launch_bounds__(256, (BN == 128) ? 4 : 5) void gemm_bt_kernel(
    const short* __restrict__ A, int lda,
    const short* __restrict__ Bt, int ldb,
    void* __restrict__ Cout, int ldc, int K, int nx, int ny, int RG,
    const float* __restrict__ cosT, const float* __restrict__ sinT)
{
  constexpr int WC = (BN == 128) ? 2 : 1;
  constexpr int MI = (BN == 128) ? 4 : 2;
  constexpr int NI = 4;
  __shared__ short Al[128*64];
  __shared__ short Bl[BN*64];
  const int tid = threadIdx.x;
  const int wid = tid >> 6;
  const int lane = tid & 63;
  const int wr = wid / WC, wc = wid % WC;
  const int lrow = lane & 15;
  const int lk   = (lane >> 4) << 3;
  const int swd  = (lrow & 7) << 3;       // read-side XOR

  // XCD-sliced, col-outer/row-inner group order (bijective; requires ny%8==0, (ny/8)%RG==0)
  int bx, by;
  {
    const int lin = blockIdx.x;
    const int xcd = lin & 7;
    const int t   = lin >> 3;            // chunk-local, [0, nx*(ny/8))
    const int rpx = ny >> 3;             // row-blocks per XCD
    const int gsz = RG * nx;
    int g   = t / gsz;
    int rem = t - g*gsz;
    int c   = rem / RG;
    int rl  = rem - c*RG;
    if (c & 1) rl = RG - 1 - rl;
    if (g & 1) c = nx - 1 - c;
    by = xcd*rpx + g*RG + rl;
    bx = c;
  }

  f32x4 acc[MI][NI];
  #pragma unroll
  for (int i=0;i<MI;i++)
    #pragma unroll
    for (int j=0;j<NI;j++) acc[i][j] = (f32x4){0.f,0.f,0.f,0.f};

  const size_t abase = (size_t)by * 128 * lda;
  const size_t bbase = (size_t)bx * BN  * ldb;

  for (int kt = 0; kt < K; kt += 64) {
    __syncthreads();
    #pragma unroll
    for (int r = 0; r < 4; ++r) {
      int l2 = (r<<8) + tid;
      int row = l2 >> 3;
      int scol = ((l2 & 7) << 3) ^ ((row & 7) << 3);
      const short* ga = A + abase + (size_t)row*lda + kt + scol;
      int lbase = (r<<11) + (wid<<9);
      __builtin_amdgcn_global_load_lds(GPTR(ga), LPTR(Al + lbase), 16, 0, 0);
    }
    #pragma unroll
    for (int r = 0; r < BN/32; ++r) {
      int l2 = (r<<8) + tid;
      int row = l2 >> 3;
      int scol = ((l2 & 7) << 3) ^ ((row & 7) << 3);
      const short* gb = Bt + bbase + (size_t)row*ldb + kt + scol;
      int lbase = (r<<11) + (wid<<9);
      __builtin_amdgcn_global_load_lds(GPTR(gb), LPTR(Bl + lbase), 16, 0, 0);
    }
    __syncthreads();

    #pragma unroll
    for (int kk = 0; kk < 64; kk += 32) {
      bf16x8 af[MI], bfr[NI];
      #pragma unroll
      for (int mi=0;mi<MI;mi++){
        int row = wr*(MI*16) + (mi<<4) + lrow;
        af[mi] = *(const bf16x8*)(Al + row*64 + ((kk + lk) ^ swd));
      }
      #pragma unroll
      for (int ni=0;ni<NI;ni++){
        int row = wc*(NI*16) + (ni<<4) + lrow;
        bfr[ni] = *(const bf16x8*)(Bl + row*64 + ((kk + lk) ^ swd));
      }
      #pragma unroll
      for (int mi=0;mi<MI;mi++)
        #pragma unroll
        for (int ni=0;ni<NI;ni++)
          acc[mi][ni] = __builtin_amdgcn_mfma_f32_16x16x32_bf16(af[mi], bfr[ni], acc[mi][ni], 0, 0, 0);
    }
  }

  const int crow0 = by*128 + wr*(MI*16);
  const int ccol0 = bx*BN  + wc*(NI*16);

  if (EPI == 2) {
    #pragma unroll
    for (int mi=0;mi<MI;mi++){
      #pragma unroll
      for (int p=0;p<NI/2;p++){
        int fcol = (ccol0>>1) + (p<<4) + lrow;
        int rowb = crow0 + (mi<<4) + ((lane>>4)<<2);
        #pragma unroll
        for (int v=0;v<4;v++){
          float g = acc[mi][2*p][v], u = acc[mi][2*p+1][v];
          float a = g * u / (1.0f + __expf(-g));
          ((short*)Cout)[(size_t)(rowb+v)*ldc + fcol] = f2bf(a);
        }
      }
    }
  } else if (EPI == 3) {
    #pragma unroll
    for (int mi=0;mi<MI;mi++){
      #pragma unroll
      for (int ni=0;ni<NI;ni++){
        int col  = ccol0 + (ni<<4) + lrow;
        int rowb = crow0 + (mi<<4) + ((lane>>4)<<2);
        bool qk = (col < 2048);
        int jhd = (col >> 1) & 31;
        #pragma unroll
        for (int v=0;v<4;v++){
          float val = acc[mi][ni][v];
          int row = rowb + v;
          int trow = row & (N_-1);             // position within batch
          float partner = __shfl_xor(val, 1, 64);
          if (qk) {
            float cc = cosT[(trow<<5)+jhd], ssn = sinT[(trow<<5)+jhd];
            float r = (lane & 1) ? (val*cc + partner*ssn) : (val*cc - partner*ssn);
            val = (col < 1024) ? r*0.125f : r;
          }
          ((short*)Cout)[(size_t)row*ldc + col] = f2bf(val);
        }
      }
    }
  } else {
    #pragma unroll
    for (int mi=0;mi<MI;mi++){
      #pragma unroll
      for (int ni=0;ni<NI;ni++){
        int col  = ccol0 + (ni<<4) + lrow;
        int rowb = crow0 + (mi<<4) + ((lane>>4)<<2);
        #pragma unroll
        for (int v=0;v<4;v++){
          float val = acc[mi][ni][v];
          int row = rowb + v;
          if (EPI == 0) ((short*)Cout)[(size_t)row*ldc + col] = f2bf(val);
          else          ((float*)Cout)[(size_t)row*ldc + col] += val;
        }
      }
    }
  }
}

// ---------------- sliding-window attention: f32-K LDS (chunk-XOR), 2 lanes/query ----------------
// Rows are global; window is clamped to the 4096-row batch segment.
#define QB_ 128
__global__ __launch_bounds__(256, 2) void attn_kernel(const short* __restrict__ qkv,
                                                      short* __restrict__ o){
  __shared__ float Kf[160*68];
  __shared__ short Vl[160*72];
  const int h  = blockIdx.y;
  const int n0 = blockIdx.x * QB_;
  const int lo = n0 & ~(N_-1);
  const int hi = lo + N_ - 1;
  const int tid = threadIdx.x;

  for (int i = tid; i < 1280; i += 256){
    int r = i >> 3, g = i & 7;
    int m = n0 - 16 + r;
    int mc = m < lo ? lo : (m > hi ? hi : m);
    bf16x8 kv = *(const bf16x8*)(qkv + (size_t)mc*3072 + 1024 + h*64 + (g<<3));
    bf16x8 vv = *(const bf16x8*)(qkv + (size_t)mc*3072 + 2048 + h*64 + (g<<3));
    int sw = ((r>>3)&3)<<1;
    float4 lof, hif;
    lof.x=bf2f(kv[0]); lof.y=bf2f(kv[1]); lof.z=bf2f(kv[2]); lof.w=bf2f(kv[3]);
    hif.x=bf2f(kv[4]); hif.y=bf2f(kv[5]); hif.z=bf2f(kv[6]); hif.w=bf2f(kv[7]);
    *(float4*)(Kf + r*68 + (((2*g)   ^ sw)<<2)) = lof;
    *(float4*)(Kf + r*68 + (((2*g+1) ^ sw)<<2)) = hif;
    *(bf16x8*)(Vl + r*72 + (g<<3)) = vv;
  }
  __syncthreads();

  const int q  = tid >> 1;
  const int dh = tid & 1;
  const int nc = n0 + q;

  const short* qp = qkv + (size_t)nc*3072 + h*64 + dh*32;
  float qr[32];
  #pragma unroll
  for (int i=0;i<4;i++){
    bf16x8 qv = *(const bf16x8*)(qp + i*8);
    #pragma unroll
    for (int t=0;t<8;t++) qr[i*8+t] = bf2f(qv[t]);
  }

  float sc[31];
  float mx = -1e30f;
  #pragma unroll
  for (int t=0;t<31;t++){
    int m = nc - 15 + t;
    int r = q + 1 + t;
    int sw = ((r>>3)&3)<<1;
    const float* kp = Kf + r*68;
    float dot = 0.f;
    #pragma unroll
    for (int i=0;i<8;i++){
      float4 kv4 = *(const float4*)(kp + (((dh*8+i)^sw)<<2));
      dot += qr[i*4+0]*kv4.x + qr[i*4+1]*kv4.y + qr[i*4+2]*kv4.z + qr[i*4+3]*kv4.w;
    }
    dot += __shfl_xor(dot, 1, 64);
    bool valid = (m>=lo) && (m<=hi);
    sc[t] = valid ? dot : -1e30f;
    mx = fmaxf(mx, sc[t]);
  }
  float sum = 0.f;
  #pragma unroll
  for (int t=0;t<31;t++){ sc[t] = __expf(sc[t]-mx); sum += sc[t]; }
  float inv = 1.0f/sum;

  float ov[32];
  #pragma unroll
  for (int i=0;i<32;i++) ov[i]=0.f;
  #pragma unroll
  for (int t=0;t<31;t++){
    const short* vp = Vl + (q + 1 + t)*72 + dh*32;
    float p = sc[t]*inv;
    #pragma unroll
    for (int i=0;i<4;i++){
      bf16x8 vv = *(const bf16x8*)(vp + i*8);
      #pragma unroll
      for (int u=0;u<8;u++) ov[i*8+u] += p * bf2f(vv[u]);
    }
  }
  short* op = o + (size_t)nc*1024 + h*64 + dh*32;
  #pragma unroll
  for (int i=0;i<4;i++){
    bf16x8 wv;
    #pragma unroll
    for (int u=0;u<8;u++) wv[u] = f2bf(ov[i*8+u]);
    *(bf16x8*)(op + i*8) = wv;
  }
}

// ---------------- final rmsnorm + head matmul (V=6), fp32 ----------------
__global__ __launch_bounds__(256) void head_kernel(const float* __restrict__ z,
                                                   const float* __restrict__ fw,
                                                   const float* __restrict__ hw,
                                                   float* __restrict__ out){
  int row = blockIdx.x, tid = threadIdx.x;
  const float* x = z + (size_t)row*D_;
  float4 v = *(const float4*)(x + tid*4);
  float ss = v.x*v.x + v.y*v.y + v.z*v.z + v.w*v.w;
  #pragma unroll
  for (int off=32; off>0; off>>=1) ss += __shfl_down(ss, off, 64);
  __shared__ float red[4];
  if ((tid & 63) == 0) red[tid>>6] = ss;
  __syncthreads();
  float ms = (red[0]+red[1]+red[2]+red[3]) * (1.0f/D_);
  float rs = rsqrtf(ms + 1e-6f);
  float4 wv = *(const float4*)(fw + tid*4);
  float h0 = v.x*rs*wv.x, h1 = v.y*rs*wv.y, h2 = v.z*rs*wv.z, h3 = v.w*rs*wv.w;
  float p[6];
  #pragma unroll
  for (int t=0;t<6;t++){
    const float* hp = hw + (size_t)(tid*4)*6 + t;
    p[t] = h0*hp[0] + h1*hp[6] + h2*hp[12] + h3*hp[18];
  }
  #pragma unroll
  for (int t=0;t<6;t++)
    #pragma unroll
    for (int off=32; off>0; off>>=1) p[t] += __shfl_down(p[t], off, 64);
  __shared__ float wred[4][6];
  if ((tid & 63) == 0)
    #pragma unroll
    for (int t=0;t<6;t++) wred[tid>>6][t] = p[t];
  __syncthreads();
  if (tid < 6)
    out[(size_t)row*6 + tid] = wred[0][tid]+wred[1][tid]+wred[2][tid]+wred[3][tid];
}

extern "C" void kernel_launch(void* const* d_in, const int* in_sizes, int n_in,
                              void* d_out, int out_size, void* d_ws, size_t ws_size,
                              hipStream_t stream)
{
  (void)in_sizes; (void)n_in; (void)out_size;
  const float* z_hat  = (const float*)d_in[0];
  const float* source = (const float*)d_in[1];
  const float* wq  = (const float*)d_in[2];
  const float* wk  = (const float*)d_in[3];
  const float* wvp = (const float*)d_in[4];
  const float* wo  = (const float*)d_in[5];
  const float* n1w = (const float*)d_in[6];
  const float* n2w = (const float*)d_in[7];
  const float* w1  = (const float*)d_in[8];
  const float* w3  = (const float*)d_in[9];
  const float* w2  = (const float*)d_in[10];
  const float* fnw = (const float*)d_in[11];
  const float* hw  = (const float*)d_in[12];
  float* out = (float*)d_out;
  char* ws = (char*)d_ws;
  dim3 tb(32,8);

  const bool fullM = (ws_size >= 219283456ULL);

  if (fullM) {
    // ---- full-M layout: 219.3 MB ----
    float* z     = (float*)(ws);                      // 67,108,864
    short* h     = (short*)(ws + 67108864);           // 33,554,432  [16384][1024] (doubles as o)
    short* qkv   = (short*)(ws + 100663296);          // 100,663,296 [16384][3072] (shared with act)
    short* act   = qkv;                               //             [16384][2752]
    short* qkvW  = (short*)(ws + 201326592);          //  6,291,456
    short* woW   = (short*)(ws + 207618048);          //  2,097,152
    short* w13W  = (short*)(ws + 201326592);          // 11,272,192  (stage B reuse)
    short* w2W   = (short*)(ws + 212598784);          //  5,636,096
    float* cosT  = (float*)(ws + 218234880);
    float* sinT  = (float*)(ws + 218759168);

    gather2_kernel<<<16896,256,0,stream>>>(z_hat, source, z, cosT, sinT);

    for (int l=0; l<NL_; l++){
      size_t wofs = (size_t)l*D_*D_;
      tconv_kernel<<<dim3(32,32,4),tb,0,stream>>>(
          wq + wofs, wk + wofs, wvp + wofs, wo + wofs,
          qkvW, qkvW + 1024*1024, qkvW + 2048*1024, woW,
          1024,1024,1024, 64,64, 0,0);
      // stage A
      rmsnorm_kernel<<<M_,256,0,stream>>>(z, n1w + l*D_, h);
      gemm_bt_kernel<3,128><<<3072,256,0,stream>>>(h,1024, qkvW,1024, qkv,3072, 1024, 24,128,16, cosT, sinT);
      attn_kernel<<<dim3(M_/QB_,H_),256,0,stream>>>(qkv, h);          // o overwrites h (h dead)
      gemm_bt_kernel<1,64><<<2048,256,0,stream>>>(h,1024, woW,1024, z,1024, 1024, 16,128,16, cosT, sinT);
      // stage B weights
      tconv_kernel<<<dim3(32,86,2),tb,0,stream>>>(
          w1 + (size_t)l*D_*FF_, w3 + (size_t)l*D_*FF_, w1, w1,
          w13W, w13W, w13W, w13W,
          1024,2752,1024, 16,32, 0,16);
      tconv_kernel<<<dim3(86,32,1),tb,0,stream>>>(
          w2 + (size_t)l*FF_*D_, w2, w2, w2,
          w2W, w2W, w2W, w2W,
          2752,1024,2752, 64,64, 0,0);
      // stage B
      rmsnorm_kernel<<<M_,256,0,stream>>>(z, n2w + l*D_, h);
      gemm_bt_kernel<2,128><<<5504,256,0,stream>>>(h,1024, w13W,1024, act,2752, 1024, 43,128,16, cosT, sinT);
      gemm_bt_kernel<1,64><<<2048,256,0,stream>>>(act,2752, w2W,2752, z,1024, 2752, 16,128,4, cosT, sinT);
    }
    head_kernel<<<M_,256,0,stream>>>(z, fnw, hw, out);

  } else {
    // ---- per-batch layout (121 MiB) ----
    float* z     = (float*)(ws);
    short* h_b   = (short*)(ws + 67108864);
    short* qkv_b = (short*)(ws + 75497472);
    short* act_b = qkv_b;
    short* o_b   = (short*)(ws + 100663296);
    short* qkvW  = (short*)(ws + 109051904);
    short* woW   = (short*)(ws + 115343360);
    short* w13W  = (short*)(ws + 109051904);
    short* w2W   = (short*)(ws + 120324096);
    float* cosT  = (float*)(ws + 125960192);
    float* sinT  = (float*)(ws + 126484480);

    gather2_kernel<<<16896,256,0,stream>>>(z_hat, source, z, cosT, sinT);

    for (int l=0; l<NL_; l++){
      size_t wofs = (size_t)l*D_*D_;
      tconv_kernel<<<dim3(32,32,4),tb,0,stream>>>(
          wq + wofs, wk + wofs, wvp + wofs, wo + wofs,
          qkvW, qkvW + 1024*1024, qkvW + 2048*1024, woW,
          1024,1024,1024, 64,64, 0,0);
      for (int b=0; b<B_; b++){
        float* zb = z + (size_t)b*N_*D_;
        rmsnorm_kernel<<<N_,256,0,stream>>>(zb, n1w + l*D_, h_b);
        gemm_bt_kernel<3,128><<<768,256,0,stream>>>(h_b,1024, qkvW,1024, qkv_b,3072, 1024, 24,32,4, cosT, sinT);
        attn_kernel<<<dim3(N_/QB_,H_),256,0,stream>>>(qkv_b, o_b);
        gemm_bt_kernel<1,64><<<512,256,0,stream>>>(o_b,1024, woW,1024, zb,1024, 1024, 16,32,4, cosT, sinT);
      }
      tconv_kernel<<<dim3(32,86,2),tb,0,stream>>>(
          w1 + (size_t)l*D_*FF_, w3 + (size_t)l*D_*FF_, w1, w1,
          w13W, w13W, w13W, w13W,
          1024,2752,1024, 16,32, 0,16);
      tconv_kernel<<<dim3(86,32,1),tb,0,stream>>>(
          w2 + (size_t)l*FF_*D_, w2, w2, w2,
          w2W, w2W, w2W, w2W,
          2752,1024,2752, 64,64, 0,0);
      for (int b=0; b<B_; b++){
        float* zb = z + (size_t)b*N_*D_;
        rmsnorm_kernel<<<N_,256,0,stream>>>(zb, n2w + l*D_, h_b);
        gemm_bt_kernel<2,128><<<1376,256,0,stream>>>(h_b,1024, w13W,1024, act_b,2752, 1024, 43,32,4, cosT, sinT);
        gemm_bt_kernel<1,64><<<512,256,0,stream>>>(act_b,2752, w2W,2752, zb,1024, 2752, 16,32,4, cosT, sinT);
      }
    }
    head_kernel<<<M_,256,0,stream>>>(z, fnw, hw, out);
  }
}

// Round 18
// 1326.375 us; speedup vs baseline: 1.1216x; 1.0288x over previous
//
#include <hip/hip_runtime.h>
#include <hip/hip_bf16.h>
#include <math.h>

#define B_ 4
#define L_ 1024
#define N_ 4096
#define D_ 1024
#define H_ 16
#define FF_ 2752
#define NL_ 2
#define HD_ 64
#define M_ (B_*N_)   // 16384

typedef short bf16x8 __attribute__((ext_vector_type(8)));
typedef float f32x4 __attribute__((ext_vector_type(4)));

__device__ __forceinline__ float bf2f(short s){
  unsigned int u = ((unsigned int)(unsigned short)s) << 16;
  union { unsigned int u; float f; } c; c.u = u; return c.f;
}
__device__ __forceinline__ short f2bf(float f){
  union { float f; unsigned int u; } c; c.f = f;
  unsigned int u = c.u;
  unsigned int r = (u + 0x7fffu + ((u >> 16) & 1u)) >> 16;
  return (short)r;
}

#define GPTR(p) ((const __attribute__((address_space(1))) void*)(p))
#define LPTR(p) ((__attribute__((address_space(3))) void*)(p))

// ---------------- gather + rope table (merged launch) ----------------
__global__ __launch_bounds__(256) void gather2_kernel(const float* __restrict__ zh,
                                                      const float* __restrict__ src,
                                                      float* __restrict__ z,
                                                      float* __restrict__ cost,
                                                      float* __restrict__ sint){
  int bid = blockIdx.x;
  if (bid < 16384) {
    int idx = bid*256 + threadIdx.x;
    int d4 = idx & (D_/4 - 1);
    int n  = (idx >> 8) & (N_-1);
    int b  = idx >> 20;
    int l  = n >> 2;
    float s = src[((size_t)b*L_ + l)*N_ + n];
    float4 zv = *(const float4*)(zh + ((size_t)b*L_ + l)*D_ + d4*4);
    float4 o; o.x=zv.x*s; o.y=zv.y*s; o.z=zv.z*s; o.w=zv.w*s;
    *(float4*)(z + ((size_t)b*N_ + n)*D_ + d4*4) = o;
  } else {
    int idx = (bid-16384)*256 + threadIdx.x;   // N_*32 = 131072
    int n = idx >> 5, j = idx & 31;
    float inv = __expf(-(float)j * (9.210340371976184f/32.0f));
    float ang = (float)n * inv;
    cost[idx] = cosf(ang);
    sint[idx] = sinf(ang);
  }
}

// -------- batched transpose + fp32->bf16 --------
__global__ void tconv_kernel(const float* __restrict__ i0, const float* __restrict__ i1,
                             const float* __restrict__ i2, const float* __restrict__ i3,
                             short* __restrict__ o0, short* __restrict__ o1,
                             short* __restrict__ o2, short* __restrict__ o3,
                             int K, int Nc, int ldo, int bs, int gs, int go0, int gostep){
  __shared__ float tile[32][33];
  const float* in = (blockIdx.z==0) ? i0 : (blockIdx.z==1) ? i1 : (blockIdx.z==2) ? i2 : i3;
  short* out      = (blockIdx.z==0) ? o0 : (blockIdx.z==1) ? o1 : (blockIdx.z==2) ? o2 : o3;
  int go = go0 + (int)blockIdx.z * gostep;
  int k0 = blockIdx.x*32, r0 = blockIdx.y*32;
  int tx = threadIdx.x, ty = threadIdx.y;
  for (int i = ty; i < 32; i += 8)
    tile[i][tx] = in[(size_t)(k0+i)*Nc + r0 + tx];
  __syncthreads();
  for (int i = ty; i < 32; i += 8){
    int rr = r0 + i;
    int orow = (rr/bs)*gs + go + (rr % bs);
    out[(size_t)orow*ldo + k0 + tx] = f2bf(tile[tx][i]);
  }
}

// ---------------- rmsnorm ----------------
__global__ __launch_bounds__(256) void rmsnorm_kernel(const float* __restrict__ z,
                                                      const float* __restrict__ w,
                                                      short* __restrict__ out){
  int row = blockIdx.x, tid = threadIdx.x;
  const float* x = z + (size_t)row*D_;
  float4 v = *(const float4*)(x + tid*4);
  float ss = v.x*v.x + v.y*v.y + v.z*v.z + v.w*v.w;
  #pragma unroll
  for (int off=32; off>0; off>>=1) ss += __shfl_down(ss, off, 64);
  __shared__ float red[4];
  if ((tid & 63) == 0) red[tid>>6] = ss;
  __syncthreads();
  float ms = (red[0]+red[1]+red[2]+red[3]) * (1.0f/D_);
  float rs = rsqrtf(ms + 1e-6f);
  float4 wv = *(const float4*)(w + tid*4);
  short4 o;
  o.x = f2bf(v.x*rs*wv.x); o.y = f2bf(v.y*rs*wv.y);
  o.z = f2bf(v.z*rs*wv.z); o.w = f2bf(v.w*rs*wv.w);
  *(short4*)(out + (size_t)row*D_ + tid*4) = o;
}

// ---------------- GEMM (2-phase 128xBN), XOR-swizzled LDS, XCD row-slice RG order ----------
// LDS layout: [row][64] with column ^ ((row&7)<<3), applied via pre-swizzled GLOBAL source
// (LDS dest linear for global_load_lds) and matching XOR on ds_read. Fragment rows have
// row&7 == lrow&7, so the involution cancels; kills the 16-way stride-128B bank conflict.
// BN=128: 4 waves/EU | BN=64: 5 waves/EU (both occupancy-verified r15/r16).
// EPI 0: store bf16 | EPI 1: fp32 += | EPI 2: swiglu pairs (BN=128) | EPI 3: rope(q,k)+qscale
template<int EPI, int BN>
__global__ __launch_bounds__(256, (BN == 128) ? 4 : 5) void gemm_bt_kernel(
    const short* __restrict__ A, int lda,
    const short* __restrict__ Bt, int ldb,
    void* __restrict__ Cout, int ldc, int K, int nx, int ny, int RG,
    const float* __restrict__ cosT, const float* __restrict__ sinT)
{
  constexpr int WC = (BN == 128) ? 2 : 1;
  constexpr int MI = (BN == 128) ? 4 : 2;
  constexpr int NI = 4;
  __shared__ short Al[128*64];
  __shared__ short Bl[BN*64];
  const int tid = threadIdx.x;
  const int wid = tid >> 6;
  const int lane = tid & 63;
  const int wr = wid / WC, wc = wid % WC;
  const int lrow = lane & 15;
  const int lk   = (lane >> 4) << 3;
  const int swd  = (lrow & 7) << 3;       // read-side XOR

  // XCD-sliced, col-outer/row-inner group order (bijective; requires ny%8==0, (ny/8)%RG==0)
  int bx, by;
  {
    const int lin = blockIdx.x;
    const int xcd = lin & 7;
    const int t   = lin >> 3;            // chunk-local, [0, nx*(ny/8))
    const int rpx = ny >> 3;             // row-blocks per XCD
    const int gsz = RG * nx;
    int g   = t / gsz;
    int rem = t - g*gsz;
    int c   = rem / RG;
    int rl  = rem - c*RG;
    if (c & 1) rl = RG - 1 - rl;
    if (g & 1) c = nx - 1 - c;
    by = xcd*rpx + g*RG + rl;
    bx = c;
  }

  f32x4 acc[MI][NI];
  #pragma unroll
  for (int i=0;i<MI;i++)
    #pragma unroll
    for (int j=0;j<NI;j++) acc[i][j] = (f32x4){0.f,0.f,0.f,0.f};

  const size_t abase = (size_t)by * 128 * lda;
  const size_t bbase = (size_t)bx * BN  * ldb;

  for (int kt = 0; kt < K; kt += 64) {
    __syncthreads();
    #pragma unroll
    for (int r = 0; r < 4; ++r) {
      int l2 = (r<<8) + tid;
      int row = l2 >> 3;
      int scol = ((l2 & 7) << 3) ^ ((row & 7) << 3);
      const short* ga = A + abase + (size_t)row*lda + kt + scol;
      int lbase = (r<<11) + (wid<<9);
      __builtin_amdgcn_global_load_lds(GPTR(ga), LPTR(Al + lbase), 16, 0, 0);
    }
    #pragma unroll
    for (int r = 0; r < BN/32; ++r) {
      int l2 = (r<<8) + tid;
      int row = l2 >> 3;
      int scol = ((l2 & 7) << 3) ^ ((row & 7) << 3);
      const short* gb = Bt + bbase + (size_t)row*ldb + kt + scol;
      int lbase = (r<<11) + (wid<<9);
      __builtin_amdgcn_global_load_lds(GPTR(gb), LPTR(Bl + lbase), 16, 0, 0);
    }
    __syncthreads();

    #pragma unroll
    for (int kk = 0; kk < 64; kk += 32) {
      bf16x8 af[MI], bfr[NI];
      #pragma unroll
      for (int mi=0;mi<MI;mi++){
        int row = wr*(MI*16) + (mi<<4) + lrow;
        af[mi] = *(const bf16x8*)(Al + row*64 + ((kk + lk) ^ swd));
      }
      #pragma unroll
      for (int ni=0;ni<NI;ni++){
        int row = wc*(NI*16) + (ni<<4) + lrow;
        bfr[ni] = *(const bf16x8*)(Bl + row*64 + ((kk + lk) ^ swd));
      }
      #pragma unroll
      for (int mi=0;mi<MI;mi++)
        #pragma unroll
        for (int ni=0;ni<NI;ni++)
          acc[mi][ni] = __builtin_amdgcn_mfma_f32_16x16x32_bf16(af[mi], bfr[ni], acc[mi][ni], 0, 0, 0);
    }
  }

  const int crow0 = by*128 + wr*(MI*16);
  const int ccol0 = bx*BN  + wc*(NI*16);

  if (EPI == 2) {
    #pragma unroll
    for (int mi=0;mi<MI;mi++){
      #pragma unroll
      for (int p=0;p<NI/2;p++){
        int fcol = (ccol0>>1) + (p<<4) + lrow;
        int rowb = crow0 + (mi<<4) + ((lane>>4)<<2);
        #pragma unroll
        for (int v=0;v<4;v++){
          float g = acc[mi][2*p][v], u = acc[mi][2*p+1][v];
          float a = g * u / (1.0f + __expf(-g));
          ((short*)Cout)[(size_t)(rowb+v)*ldc + fcol] = f2bf(a);
        }
      }
    }
  } else if (EPI == 3) {
    #pragma unroll
    for (int mi=0;mi<MI;mi++){
      #pragma unroll
      for (int ni=0;ni<NI;ni++){
        int col  = ccol0 + (ni<<4) + lrow;
        int rowb = crow0 + (mi<<4) + ((lane>>4)<<2);
        bool qk = (col < 2048);
        int jhd = (col >> 1) & 31;
        #pragma unroll
        for (int v=0;v<4;v++){
          float val = acc[mi][ni][v];
          int row = rowb + v;
          int trow = row & (N_-1);             // position within batch
          float partner = __shfl_xor(val, 1, 64);
          if (qk) {
            float cc = cosT[(trow<<5)+jhd], ssn = sinT[(trow<<5)+jhd];
            float r = (lane & 1) ? (val*cc + partner*ssn) : (val*cc - partner*ssn);
            val = (col < 1024) ? r*0.125f : r;
          }
          ((short*)Cout)[(size_t)row*ldc + col] = f2bf(val);
        }
      }
    }
  } else {
    #pragma unroll
    for (int mi=0;mi<MI;mi++){
      #pragma unroll
      for (int ni=0;ni<NI;ni++){
        int col  = ccol0 + (ni<<4) + lrow;
        int rowb = crow0 + (mi<<4) + ((lane>>4)<<2);
        #pragma unroll
        for (int v=0;v<4;v++){
          float val = acc[mi][ni][v];
          int row = rowb + v;
          if (EPI == 0) ((short*)Cout)[(size_t)row*ldc + col] = f2bf(val);
          else          ((float*)Cout)[(size_t)row*ldc + col] += val;
        }
      }
    }
  }
}

// ---------------- sliding-window attention: f32-K LDS (chunk-XOR), 2 lanes/query ----------------
// Rows are global; window is clamped to the 4096-row batch segment.
#define QB_ 128
__global__ __launch_bounds__(256, 2) void attn_kernel(const short* __restrict__ qkv,
                                                      short* __restrict__ o){
  __shared__ float Kf[160*68];
  __shared__ short Vl[160*72];
  const int h  = blockIdx.y;
  const int n0 = blockIdx.x * QB_;
  const int lo = n0 & ~(N_-1);
  const int hi = lo + N_ - 1;
  const int tid = threadIdx.x;

  for (int i = tid; i < 1280; i += 256){
    int r = i >> 3, g = i & 7;
    int m = n0 - 16 + r;
    int mc = m < lo ? lo : (m > hi ? hi : m);
    bf16x8 kv = *(const bf16x8*)(qkv + (size_t)mc*3072 + 1024 + h*64 + (g<<3));
    bf16x8 vv = *(const bf16x8*)(qkv + (size_t)mc*3072 + 2048 + h*64 + (g<<3));
    int sw = ((r>>3)&3)<<1;
    float4 lof, hif;
    lof.x=bf2f(kv[0]); lof.y=bf2f(kv[1]); lof.z=bf2f(kv[2]); lof.w=bf2f(kv[3]);
    hif.x=bf2f(kv[4]); hif.y=bf2f(kv[5]); hif.z=bf2f(kv[6]); hif.w=bf2f(kv[7]);
    *(float4*)(Kf + r*68 + (((2*g)   ^ sw)<<2)) = lof;
    *(float4*)(Kf + r*68 + (((2*g+1) ^ sw)<<2)) = hif;
    *(bf16x8*)(Vl + r*72 + (g<<3)) = vv;
  }
  __syncthreads();

  const int q  = tid >> 1;
  const int dh = tid & 1;
  const int nc = n0 + q;

  const short* qp = qkv + (size_t)nc*3072 + h*64 + dh*32;
  float qr[32];
  #pragma unroll
  for (int i=0;i<4;i++){
    bf16x8 qv = *(const bf16x8*)(qp + i*8);
    #pragma unroll
    for (int t=0;t<8;t++) qr[i*8+t] = bf2f(qv[t]);
  }

  float sc[31];
  float mx = -1e30f;
  #pragma unroll
  for (int t=0;t<31;t++){
    int m = nc - 15 + t;
    int r = q + 1 + t;
    int sw = ((r>>3)&3)<<1;
    const float* kp = Kf + r*68;
    float dot = 0.f;
    #pragma unroll
    for (int i=0;i<8;i++){
      float4 kv4 = *(const float4*)(kp + (((dh*8+i)^sw)<<2));
      dot += qr[i*4+0]*kv4.x + qr[i*4+1]*kv4.y + qr[i*4+2]*kv4.z + qr[i*4+3]*kv4.w;
    }
    dot += __shfl_xor(dot, 1, 64);
    bool valid = (m>=lo) && (m<=hi);
    sc[t] = valid ? dot : -1e30f;
    mx = fmaxf(mx, sc[t]);
  }
  float sum = 0.f;
  #pragma unroll
  for (int t=0;t<31;t++){ sc[t] = __expf(sc[t]-mx); sum += sc[t]; }
  float inv = 1.0f/sum;

  float ov[32];
  #pragma unroll
  for (int i=0;i<32;i++) ov[i]=0.f;
  #pragma unroll
  for (int t=0;t<31;t++){
    const short* vp = Vl + (q + 1 + t)*72 + dh*32;
    float p = sc[t]*inv;
    #pragma unroll
    for (int i=0;i<4;i++){
      bf16x8 vv = *(const bf16x8*)(vp + i*8);
      #pragma unroll
      for (int u=0;u<8;u++) ov[i*8+u] += p * bf2f(vv[u]);
    }
  }
  short* op = o + (size_t)nc*1024 + h*64 + dh*32;
  #pragma unroll
  for (int i=0;i<4;i++){
    bf16x8 wv;
    #pragma unroll
    for (int u=0;u<8;u++) wv[u] = f2bf(ov[i*8+u]);
    *(bf16x8*)(op + i*8) = wv;
  }
}

// ---------------- final rmsnorm + head matmul (V=6), fp32 ----------------
__global__ __launch_bounds__(256) void head_kernel(const float* __restrict__ z,
                                                   const float* __restrict__ fw,
                                                   const float* __restrict__ hw,
                                                   float* __restrict__ out){
  int row = blockIdx.x, tid = threadIdx.x;
  const float* x = z + (size_t)row*D_;
  float4 v = *(const float4*)(x + tid*4);
  float ss = v.x*v.x + v.y*v.y + v.z*v.z + v.w*v.w;
  #pragma unroll
  for (int off=32; off>0; off>>=1) ss += __shfl_down(ss, off, 64);
  __shared__ float red[4];
  if ((tid & 63) == 0) red[tid>>6] = ss;
  __syncthreads();
  float ms = (red[0]+red[1]+red[2]+red[3]) * (1.0f/D_);
  float rs = rsqrtf(ms + 1e-6f);
  float4 wv = *(const float4*)(fw + tid*4);
  float h0 = v.x*rs*wv.x, h1 = v.y*rs*wv.y, h2 = v.z*rs*wv.z, h3 = v.w*rs*wv.w;
  float p[6];
  #pragma unroll
  for (int t=0;t<6;t++){
    const float* hp = hw + (size_t)(tid*4)*6 + t;
    p[t] = h0*hp[0] + h1*hp[6] + h2*hp[12] + h3*hp[18];
  }
  #pragma unroll
  for (int t=0;t<6;t++)
    #pragma unroll
    for (int off=32; off>0; off>>=1) p[t] += __shfl_down(p[t], off, 64);
  __shared__ float wred[4][6];
  if ((tid & 63) == 0)
    #pragma unroll
    for (int t=0;t<6;t++) wred[tid>>6][t] = p[t];
  __syncthreads();
  if (tid < 6)
    out[(size_t)row*6 + tid] = wred[0][tid]+wred[1][tid]+wred[2][tid]+wred[3][tid];
}

extern "C" void kernel_launch(void* const* d_in, const int* in_sizes, int n_in,
                              void* d_out, int out_size, void* d_ws, size_t ws_size,
                              hipStream_t stream)
{
  (void)in_sizes; (void)n_in; (void)out_size;
  const float* z_hat  = (const float*)d_in[0];
  const float* source = (const float*)d_in[1];
  const float* wq  = (const float*)d_in[2];
  const float* wk  = (const float*)d_in[3];
  const float* wvp = (const float*)d_in[4];
  const float* wo  = (const float*)d_in[5];
  const float* n1w = (const float*)d_in[6];
  const float* n2w = (const float*)d_in[7];
  const float* w1  = (const float*)d_in[8];
  const float* w3  = (const float*)d_in[9];
  const float* w2  = (const float*)d_in[10];
  const float* fnw = (const float*)d_in[11];
  const float* hw  = (const float*)d_in[12];
  float* out = (float*)d_out;
  char* ws = (char*)d_ws;
  dim3 tb(32,8);

  const bool fullM = (ws_size >= 219283456ULL);

  if (fullM) {
    // ---- full-M layout: 219.3 MB ----
    float* z     = (float*)(ws);                      // 67,108,864
    short* h     = (short*)(ws + 67108864);           // 33,554,432  [16384][1024] (doubles as o)
    short* qkv   = (short*)(ws + 100663296);          // 100,663,296 [16384][3072] (shared with act)
    short* act   = qkv;                               //             [16384][2752]
    short* qkvW  = (short*)(ws + 201326592);          //  6,291,456
    short* woW   = (short*)(ws + 207618048);          //  2,097,152
    short* w13W  = (short*)(ws + 201326592);          // 11,272,192  (stage B reuse)
    short* w2W   = (short*)(ws + 212598784);          //  5,636,096
    float* cosT  = (float*)(ws + 218234880);
    float* sinT  = (float*)(ws + 218759168);

    gather2_kernel<<<16896,256,0,stream>>>(z_hat, source, z, cosT, sinT);

    for (int l=0; l<NL_; l++){
      size_t wofs = (size_t)l*D_*D_;
      tconv_kernel<<<dim3(32,32,4),tb,0,stream>>>(
          wq + wofs, wk + wofs, wvp + wofs, wo + wofs,
          qkvW, qkvW + 1024*1024, qkvW + 2048*1024, woW,
          1024,1024,1024, 64,64, 0,0);
      // stage A
      rmsnorm_kernel<<<M_,256,0,stream>>>(z, n1w + l*D_, h);
      gemm_bt_kernel<3,128><<<3072,256,0,stream>>>(h,1024, qkvW,1024, qkv,3072, 1024, 24,128,16, cosT, sinT);
      attn_kernel<<<dim3(M_/QB_,H_),256,0,stream>>>(qkv, h);          // o overwrites h (h dead)
      gemm_bt_kernel<1,128><<<1024,256,0,stream>>>(h,1024, woW,1024, z,1024, 1024, 8,128,8, cosT, sinT);
      // stage B weights
      tconv_kernel<<<dim3(32,86,2),tb,0,stream>>>(
          w1 + (size_t)l*D_*FF_, w3 + (size_t)l*D_*FF_, w1, w1,
          w13W, w13W, w13W, w13W,
          1024,2752,1024, 16,32, 0,16);
      tconv_kernel<<<dim3(86,32,1),tb,0,stream>>>(
          w2 + (size_t)l*FF_*D_, w2, w2, w2,
          w2W, w2W, w2W, w2W,
          2752,1024,2752, 64,64, 0,0);
      // stage B
      rmsnorm_kernel<<<M_,256,0,stream>>>(z, n2w + l*D_, h);
      gemm_bt_kernel<2,128><<<5504,256,0,stream>>>(h,1024, w13W,1024, act,2752, 1024, 43,128,16, cosT, sinT);
      gemm_bt_kernel<1,128><<<1024,256,0,stream>>>(act,2752, w2W,2752, z,1024, 2752, 8,128,4, cosT, sinT);
    }
    head_kernel<<<M_,256,0,stream>>>(z, fnw, hw, out);

  } else {
    // ---- per-batch layout (121 MiB) ----
    float* z     = (float*)(ws);
    short* h_b   = (short*)(ws + 67108864);
    short* qkv_b = (short*)(ws + 75497472);
    short* act_b = qkv_b;
    short* o_b   = (short*)(ws + 100663296);
    short* qkvW  = (short*)(ws + 109051904);
    short* woW   = (short*)(ws + 115343360);
    short* w13W  = (short*)(ws + 109051904);
    short* w2W   = (short*)(ws + 120324096);
    float* cosT  = (float*)(ws + 125960192);
    float* sinT  = (float*)(ws + 126484480);

    gather2_kernel<<<16896,256,0,stream>>>(z_hat, source, z, cosT, sinT);

    for (int l=0; l<NL_; l++){
      size_t wofs = (size_t)l*D_*D_;
      tconv_kernel<<<dim3(32,32,4),tb,0,stream>>>(
          wq + wofs, wk + wofs, wvp + wofs, wo + wofs,
          qkvW, qkvW + 1024*1024, qkvW + 2048*1024, woW,
          1024,1024,1024, 64,64, 0,0);
      for (int b=0; b<B_; b++){
        float* zb = z + (size_t)b*N_*D_;
        rmsnorm_kernel<<<N_,256,0,stream>>>(zb, n1w + l*D_, h_b);
        gemm_bt_kernel<3,128><<<768,256,0,stream>>>(h_b,1024, qkvW,1024, qkv_b,3072, 1024, 24,32,4, cosT, sinT);
        attn_kernel<<<dim3(N_/QB_,H_),256,0,stream>>>(qkv_b, o_b);
        gemm_bt_kernel<1,64><<<512,256,0,stream>>>(o_b,1024, woW,1024, zb,1024, 1024, 16,32,4, cosT, sinT);
      }
      tconv_kernel<<<dim3(32,86,2),tb,0,stream>>>(
          w1 + (size_t)l*D_*FF_, w3 + (size_t)l*D_*FF_, w1, w1,
          w13W, w13W, w13W, w13W,
          1024,2752,1024, 16,32, 0,16);
      tconv_kernel<<<dim3(86,32,1),tb,0,stream>>>(
          w2 + (size_t)l*FF_*D_, w2, w2, w2,
          w2W, w2W, w2W, w2W,
          2752,1024,2752, 64,64, 0,0);
      for (int b=0; b<B_; b++){
        float* zb = z + (size_t)b*N_*D_;
        rmsnorm_kernel<<<N_,256,0,stream>>>(zb, n2w + l*D_, h_b);
        gemm_bt_kernel<2,128><<<1376,256,0,stream>>>(h_b,1024, w13W,1024, act_b,2752, 1024, 43,32,4, cosT, sinT);
        gemm_bt_kernel<1,64><<<512,256,0,stream>>>(act_b,2752, w2W,2752, zb,1024, 2752, 16,32,4, cosT, sinT);
      }
    }
    head_kernel<<<M_,256,0,stream>>>(z, fnw, hw, out);
  }
}